// Round 4
// baseline (243.599 us; speedup 1.0000x reference)
//
#include <hip/hip_runtime.h>
#include <stdint.h>
#include <stddef.h>

#define NB 4
#define NC 320
#define NH 128
#define NW 240
#define ND 49
#define HW (NH * NW)          // 30720
#define CC 32                 // channels per chunk
#define NCHUNK (NC / CC)      // 10
#define XMAXC 80              // X cols per segment
#define YMAXC 128             // Y window capacity
#define BUFSZ ((XMAXC + YMAXC) * CC)   // 6656 shorts = 13312 B

typedef float f32x4 __attribute__((ext_vector_type(4)));
typedef short s16x8 __attribute__((ext_vector_type(8)));

__device__ __forceinline__ uint32_t bf16r(float f) {
  uint32_t u = __builtin_bit_cast(uint32_t, f);
  return (u + 0x7FFFu + ((u >> 16) & 1u)) >> 16;  // RNE f32 -> bf16
}
__device__ __forceinline__ int swz(int w) { return (w ^ (w >> 2)) & 3; }

// One (b,h) row, one of 3 segments of 5 wi-tiles.
// SEG s: wi tiles 5s..5s+4, X cols [80s, 80s+80), Y cols [YW0, YW0+YCOLS).
template <int SEG>
__device__ __forceinline__ void cv_body(const float* __restrict__ xrow,
                                        const float* __restrict__ yrow,
                                        float* __restrict__ orow,
                                        short* lds, const int tid) {
  constexpr int WT0   = SEG * 5;
  constexpr int XW0   = SEG * 80;
  constexpr int YW0   = (SEG == 0) ? 0 : SEG * 80 - 48;
  constexpr int YCOLS = (SEG == 0) ? 80 : 128;
  constexpr int NW4X  = XMAXC / 4;          // 20
  constexpr int NW4Y  = YCOLS / 4;          // 20 or 32
  constexpr int UPW   = NW4X + NW4Y;        // units per wave (40 or 52) <= 64

  const int wave = tid >> 6;
  const int l = tid & 63;
  const int m = l & 15;   // fragment row/col
  const int q = l >> 4;   // k-group

  // Stage unit = (c8 = wave, w4 = l): 8 x dwordx4 loads -> 4 x b128 writes.
  // Perfectly wave-balanced; lanes contiguous in w -> coalesced runs.
  const bool act = l < UPW;
  const bool isX = l < NW4X;
  const int u_w4 = isX ? l : (l - NW4X);
  const float* u_src = (isX ? xrow + XW0 : yrow + YW0) + u_w4 * 4;
  const int u_lds_off = isX ? 0 : XMAXC * CC;

  f32x4 acc[2][4] = {};
  f32x4 L[8];     // in-flight f32 chunk (issued 1 iteration early)
  s16x8 P[4];     // converted bf16, written after compute

  auto load_chunk = [&](int chunk) {
    const float* p = u_src + (size_t)(chunk * CC + wave * 8) * HW;
#pragma unroll
    for (int j = 0; j < 8; ++j) L[j] = *(const f32x4*)(p + (size_t)j * HW);
  };
  auto convert = [&]() {       // waits (counted) only on L's loads
#pragma unroll
    for (int ww = 0; ww < 4; ++ww) {
      s16x8 s;
#pragma unroll
      for (int j = 0; j < 8; ++j) s[j] = (short)bf16r(L[j][ww]);
      P[ww] = s;
    }
  };
  auto write_P = [&](int buf) {
    short* base = lds + buf * BUFSZ + u_lds_off;
#pragma unroll
    for (int idx = 0; idx < 4; ++idx) {
      const int ww = (idx + u_w4) & 3;      // rotated: bank-spread writes
      const int w = u_w4 * 4 + ww;
      *(s16x8*)&base[w * CC + (((wave ^ swz(w)) & 3) * 8)] = P[ww];
    }
  };

  auto compute = [&](int buf) {
    const short* bx = lds + buf * BUFSZ;
    const short* by = lds + buf * BUFSZ + XMAXC * CC;
#pragma unroll
    for (int i = 0; i < 2; ++i) {
      const int wtl = wave + i * 4;         // local tile 0..4
      if (wtl > 4) continue;                // only wave0 runs i=1
      const int wt = WT0 + wtl;
      const int war = wtl * 16 + m;
      const s16x8 a = *(const s16x8*)&bx[war * CC + ((q ^ swz(war)) * 8)];
#pragma unroll
      for (int ss = 0; ss < 4; ++ss) {
        const int st = wt - 3 + ss;
        if (SEG > 0 || st >= 0) {           // SEG>0: st >= 2 always
          const int wbr = st * 16 + m - YW0;
          const s16x8 bb = *(const s16x8*)&by[wbr * CC + ((q ^ swz(wbr)) * 8)];
          acc[i][ss] = __builtin_amdgcn_mfma_f32_16x16x32_bf16(a, bb, acc[i][ss], 0, 0, 0);
        }
      }
    }
  };

  // Prologue: chunk0 staged directly (one exposed latency), chunk1 in flight.
  if (act) { load_chunk(0); convert(); load_chunk(1); write_P(0); }
  __syncthreads();

  for (int k = 0; k < NCHUNK; ++k) {
    if (act && k + 1 < NCHUNK) {
      convert();                            // chunk k+1: arrived ~1 iter ago
      if (k + 2 < NCHUNK) load_chunk(k + 2);  // stays in flight across barriers
    }
    compute(k & 1);
    if (act && k + 1 < NCHUNK) write_P((k + 1) & 1);
    __syncthreads();
  }

  // Epilogue: d = wi - wj; virtual tiles (st<0, SEG==0) emit the w<d zeros.
#pragma unroll
  for (int i = 0; i < 2; ++i) {
    const int wtl = wave + i * 4;
    if (wtl > 4) continue;
    const int wt = WT0 + wtl;
#pragma unroll
    for (int ss = 0; ss < 4; ++ss) {
      const int st = wt - 3 + ss;
      const int wj = st * 16 + m;
#pragma unroll
      for (int r = 0; r < 4; ++r) {
        const int wi = wt * 16 + q * 4 + r;   // C/D: row = (lane>>4)*4 + reg
        const int d = wi - wj;
        if (d >= 0 && d < ND) {
          const float v = (st >= 0) ? acc[i][ss][r] : 0.0f;
          orow[(size_t)d * (NB * HW) + wi] = v;
        }
      }
    }
  }
}

__global__ __launch_bounds__(256)
__attribute__((amdgpu_waves_per_eu(4, 4)))   // pin 128-VGPR budget, no spill-for-occupancy
void cv_kernel(const float* __restrict__ X,
               const float* __restrict__ Y,
               float* __restrict__ O) {
  __shared__ short lds[2 * BUFSZ];  // 26624 B
  const int tid = threadIdx.x;
  const int bid = blockIdx.x;
  // XCD-chunked bijective swizzle (1536 = 8*192): a row's 3 segments are
  // logical-consecutive -> same XCD, so the Y band overlap hits that L2.
  const int logical = (bid & 7) * 192 + (bid >> 3);
  const int row = logical / 3;    // 0..511 = b*128 + h
  const int seg = logical % 3;
  const int b = row >> 7, h = row & 127;
  const float* xrow = X + (size_t)b * NC * HW + (size_t)h * NW;
  const float* yrow = Y + (size_t)b * NC * HW + (size_t)h * NW;
  float* orow = O + ((size_t)b * NH + h) * NW;
  if (seg == 0)      cv_body<0>(xrow, yrow, orow, lds, tid);
  else if (seg == 1) cv_body<1>(xrow, yrow, orow, lds, tid);
  else               cv_body<2>(xrow, yrow, orow, lds, tid);
}

extern "C" void kernel_launch(void* const* d_in, const int* in_sizes, int n_in,
                              void* d_out, int out_size, void* d_ws, size_t ws_size,
                              hipStream_t stream) {
  const float* x = (const float*)d_in[0];
  const float* y = (const float*)d_in[1];
  float* out = (float*)d_out;
  cv_kernel<<<dim3(1536), dim3(256), 0, stream>>>(x, y, out);
}

// Round 5
// 79.040 us; speedup vs baseline: 3.0820x; 3.0820x over previous
//
#include <hip/hip_runtime.h>
#include <stdint.h>
#include <stddef.h>

#define NB 4
#define NC 320
#define NH 128
#define NW 240
#define ND 49
#define HW (NH * NW)          // 30720
#define CC 32                 // channels per chunk
#define NCHUNK (NC / CC)      // 10
#define XWORDS 2560           // X region: 32 ch * 20 units * 4 f32
#define BUFWORDS 6656         // X 2560 + Y max 4096 f32
#define CBYTES ((size_t)CC * HW * 4)   // global stride per chunk

typedef float f32x4 __attribute__((ext_vector_type(4)));
typedef short s16x8 __attribute__((ext_vector_type(8)));

// HBM -> LDS DMA, 16 B/lane, LDS dest = uniform base + lane*16 (linear).
__device__ __forceinline__ void gload_lds16(const void* g, void* l) {
  __builtin_amdgcn_global_load_lds(
      (const __attribute__((address_space(1))) void*)g,
      (__attribute__((address_space(3))) void*)l, 16, 0, 0);
}

// 8 x f32 -> bf16x8 via v_cvt_pk_bf16_f32 (gfx950; lo=src0, hi=src1).
__device__ __forceinline__ s16x8 pack8(const float* f) {
  union { uint32_t u[4]; s16x8 v; } r;
#pragma unroll
  for (int t = 0; t < 4; ++t)
    asm("v_cvt_pk_bf16_f32 %0, %1, %2"
        : "=v"(r.u[t]) : "v"(f[2 * t]), "v"(f[2 * t + 1]));
  return r.v;
}

// One (b,h) row, one of 3 segments of 5 wi-tiles.
// SEG s: wi tiles 5s..5s+4, X cols [80s,80s+80), Y cols [YW0,YW0+YCOLS).
// LDS layouts (f32, 16B units = 4 consecutive w of one channel):
//   X: unit (c, u) holds w4 = (u - 5*qc) mod 20,  qc=(c>>3)&3  [mod-rotation]
//   Y (128 cols): unit (c, u) holds w4 = u ^ (qc<<1)           [XOR]
// Both make the wave's 8x ds_read_b32 fragment reads ~2-way (free).
template <int SEG>
__device__ __forceinline__ void cv_body(const float* __restrict__ xrow,
                                        const float* __restrict__ yrow,
                                        float* __restrict__ orow,
                                        float* lds, const int tid) {
  constexpr int WT0 = SEG * 5;
  constexpr int XW0 = SEG * 80;
  constexpr int YW0 = (SEG == 0) ? 0 : SEG * 80 - 48;
  constexpr int NXI = 10;                      // X DMA instrs (640 units)
  constexpr int NYI = (SEG == 0) ? 10 : 16;    // Y DMA instrs
  constexpr int YN4 = (SEG == 0) ? 20 : 32;    // Y units per channel
  constexpr int NINSTR = NXI + NYI;
  constexpr int KWAVE = (NINSTR + 3) / 4;      // DMA instrs per wave

  const int wave = tid >> 6;
  const int l = tid & 63;
  const int m = l & 15;   // fragment row/col
  const int q = l >> 4;   // k-group (8 channels)

  // ---- DMA slot setup: per-lane global source for each assigned instr.
  const char* pv[KWAVE];
  int loff[KWAVE];
#pragma unroll
  for (int ii = 0; ii < KWAVE; ++ii) {
    int i = wave * KWAVE + ii;
    if (i >= NINSTR) i = 0;                    // dummy (never issued)
    const float* p;
    int lo;
    if (i < NXI) {                             // X slot
      const int s = i * 64 + l;                // LDS 16B-slot index
      const int c = s / 20, u = s - c * 20;
      const int qc = (c >> 3) & 3;
      int w4 = u - 5 * qc; if (w4 < 0) w4 += 20;
      p = xrow + (size_t)c * HW + (XW0 + w4 * 4);
      lo = i * 256;
    } else {                                   // Y slot
      const int s = (i - NXI) * 64 + l;
      int c, u, w4;
      if (YN4 == 32) { c = s >> 5; u = s & 31; w4 = u ^ (((c >> 3) & 3) << 1); }
      else { c = s / 20; u = s - c * 20; const int qc = (c >> 3) & 3;
             w4 = u - 5 * qc; if (w4 < 0) w4 += 20; }
      p = yrow + (size_t)c * HW + (YW0 + w4 * 4);
      lo = XWORDS + (i - NXI) * 256;
    }
    pv[ii] = (const char*)p;
    loff[ii] = lo;
  }
  int kc = NINSTR - wave * KWAVE;              // live instrs this wave (uniform)
  if (kc > KWAVE) kc = KWAVE;
  if (kc < 0) kc = 0;

  auto issue = [&](int buf) {                  // ~7 instrs, zero VGPR staging
#pragma unroll
    for (int ii = 0; ii < KWAVE; ++ii) {
      if (ii < kc) {
        gload_lds16(pv[ii], lds + buf * BUFWORDS + loff[ii]);
        pv[ii] += CBYTES;
      }
    }
  };

  f32x4 acc[2][4] = {};

  auto compute = [&](int buf) {
    const float* BX = lds + buf * BUFWORDS;
    const float* BY = BX + XWORDS;
#pragma unroll
    for (int i = 0; i < 2; ++i) {
      const int wtl = wave + i * 4;            // local tile 0..4
      if (wtl > 4) continue;                   // only wave0 runs i=1
      float fa[8];
      {
        const int w4a = wtl * 4 + (m >> 2);
        int ua = w4a + 5 * q; if (ua >= 20) ua -= 20;
        const int base = q * 640 + ua * 4 + (m & 3);
#pragma unroll
        for (int j = 0; j < 8; ++j) fa[j] = BX[base + j * 80];
      }
      const s16x8 a = pack8(fa);
#pragma unroll
      for (int ss = 0; ss < 4; ++ss) {
        const int st = WT0 + wtl - 3 + ss;
        if (SEG > 0 || st >= 0) {              // SEG>0: st always >= 2
          float fb[8];
          const int w4b = ((st * 16 - YW0) >> 2) + (m >> 2);
          if (YN4 == 32) {
            const int ub = w4b ^ (q << 1);
            const int base = q * 1024 + ub * 4 + (m & 3);
#pragma unroll
            for (int j = 0; j < 8; ++j) fb[j] = BY[base + j * 128];
          } else {
            int ub = w4b + 5 * q; if (ub >= 20) ub -= 20;
            const int base = q * 640 + ub * 4 + (m & 3);
#pragma unroll
            for (int j = 0; j < 8; ++j) fb[j] = BY[base + j * 80];
          }
          const s16x8 b = pack8(fb);
          acc[i][ss] = __builtin_amdgcn_mfma_f32_16x16x32_bf16(a, b, acc[i][ss], 0, 0, 0);
        }
      }
    }
  };

  // Prologue: DMA chunk0 -> buf0; barrier drains vmcnt (one exposed latency).
  issue(0);
  __syncthreads();
  for (int k = 0; k < NCHUNK; ++k) {
    if (k + 1 < NCHUNK) issue((k + 1) & 1);    // in flight across compute(k)
    compute(k & 1);
    __syncthreads();                           // drains vmcnt -> chunk k+1 ready
  }

  // Epilogue: d = wi - wj; virtual tiles (st<0, SEG0) emit the w<d zeros.
#pragma unroll
  for (int i = 0; i < 2; ++i) {
    const int wtl = wave + i * 4;
    if (wtl > 4) continue;
    const int wt = WT0 + wtl;
#pragma unroll
    for (int ss = 0; ss < 4; ++ss) {
      const int st = wt - 3 + ss;
      const int wj = st * 16 + m;
#pragma unroll
      for (int r = 0; r < 4; ++r) {
        const int wi = wt * 16 + q * 4 + r;    // C/D: row=(lane>>4)*4+reg (m89)
        const int d = wi - wj;
        if (d >= 0 && d < ND) {
          const float v = (st >= 0) ? acc[i][ss][r] : 0.0f;
          orow[(size_t)d * (NB * HW) + wi] = v;
        }
      }
    }
  }
}

__global__ __launch_bounds__(256) void cv_kernel(const float* __restrict__ X,
                                                 const float* __restrict__ Y,
                                                 float* __restrict__ O) {
  __shared__ float lds[2 * BUFWORDS];  // 53248 B -> 3 blocks/CU
  const int tid = threadIdx.x;
  const int bid = blockIdx.x;
  // XCD-chunked bijective swizzle (1536 = 8*192): a row's 3 segments are
  // logical-consecutive -> same XCD L2 absorbs the Y band overlap.
  const int logical = (bid & 7) * 192 + (bid >> 3);
  const int row = logical / 3;    // 0..511 = b*128 + h
  const int seg = logical % 3;
  const int b = row >> 7, h = row & 127;
  const float* xrow = X + (size_t)b * NC * HW + (size_t)h * NW;
  const float* yrow = Y + (size_t)b * NC * HW + (size_t)h * NW;
  float* orow = O + ((size_t)b * NH + h) * NW;
  if (seg == 0)      cv_body<0>(xrow, yrow, orow, lds, tid);
  else if (seg == 1) cv_body<1>(xrow, yrow, orow, lds, tid);
  else               cv_body<2>(xrow, yrow, orow, lds, tid);
}

extern "C" void kernel_launch(void* const* d_in, const int* in_sizes, int n_in,
                              void* d_out, int out_size, void* d_ws, size_t ws_size,
                              hipStream_t stream) {
  const float* x = (const float*)d_in[0];
  const float* y = (const float*)d_in[1];
  float* out = (float*)d_out;
  cv_kernel<<<dim3(1536), dim3(256), 0, stream>>>(x, y, out);
}

// Round 6
// 75.863 us; speedup vs baseline: 3.2110x; 1.0419x over previous
//
#include <hip/hip_runtime.h>
#include <stdint.h>
#include <stddef.h>

#define NB 4
#define NC 320
#define NH 128
#define NW 240
#define ND 49
#define HW (NH * NW)          // 30720
#define CC 32                 // channels per chunk
#define NCHUNK (NC / CC)      // 10
#define XWORDS 2560           // X region: 32 ch * 20 units * 4 f32
#define BUFWORDS 6656         // X 2560 + Y max 4096 f32
#define CBYTES ((size_t)CC * HW * 4)   // global stride per chunk

typedef float f32x4 __attribute__((ext_vector_type(4)));
typedef short s16x8 __attribute__((ext_vector_type(8)));

// HBM -> LDS DMA, 16 B/lane, LDS dest = uniform base + lane*16 (linear).
__device__ __forceinline__ void gload_lds16(const void* g, void* l) {
  __builtin_amdgcn_global_load_lds(
      (const __attribute__((address_space(1))) void*)g,
      (__attribute__((address_space(3))) void*)l, 16, 0, 0);
}

// Counted VMEM wait (T4): keeps newest chunk's DMAs in flight. In-order
// vmcnt retirement (m135) => waits exactly for the older chunk.
template <int N> __device__ __forceinline__ void waitcnt_vm() {
  asm volatile("s_waitcnt vmcnt(%0)" ::"i"(N) : "memory");
  __builtin_amdgcn_sched_barrier(0);   // rule #18: no hoisting past the wait
}

// 8 x f32 -> bf16x8 via v_cvt_pk_bf16_f32 (gfx950; lo=src0, hi=src1).
__device__ __forceinline__ s16x8 pack8(const float* f) {
  union { uint32_t u[4]; s16x8 v; } r;
#pragma unroll
  for (int t = 0; t < 4; ++t)
    asm("v_cvt_pk_bf16_f32 %0, %1, %2"
        : "=v"(r.u[t]) : "v"(f[2 * t]), "v"(f[2 * t + 1]));
  return r.v;
}

// One (b,h) row, one of 3 segments of 5 wi-tiles.
// SEG s: wi tiles 5s..5s+4, X cols [80s,80s+80), Y cols [YW0,YW0+YCOLS).
// LDS layouts (f32, 16B units = 4 consecutive w of one channel):
//   X: unit (c, u) holds w4 = (u - 5*qc) mod 20,  qc=(c>>3)&3  [mod-rotation]
//   Y (128 cols): unit (c, u) holds w4 = u ^ (qc<<1)           [XOR]
// Both make the wave's 8x ds_read_b32 fragment reads ~2-way (free).
template <int SEG>
__device__ __forceinline__ void cv_body(const float* __restrict__ xrow,
                                        const float* __restrict__ yrow,
                                        float* __restrict__ orow,
                                        float* lds, const int tid) {
  constexpr int WT0 = SEG * 5;
  constexpr int XW0 = SEG * 80;
  constexpr int YW0 = (SEG == 0) ? 0 : SEG * 80 - 48;
  constexpr int NXI = 10;                      // X DMA instrs (640 units)
  constexpr int NYI = (SEG == 0) ? 10 : 16;    // Y DMA instrs
  constexpr int YN4 = (SEG == 0) ? 20 : 32;    // Y units per channel
  constexpr int NINSTR = NXI + NYI;
  constexpr int KWAVE = (NINSTR + 3) / 4;      // DMA instrs per wave

  const int wave = tid >> 6;
  const int l = tid & 63;
  const int m = l & 15;   // fragment row/col
  const int q = l >> 4;   // k-group (8 channels)

  // ---- DMA slot setup: per-lane global source for each assigned instr.
  const char* pv[KWAVE];
  int loff[KWAVE];
#pragma unroll
  for (int ii = 0; ii < KWAVE; ++ii) {
    int i = wave * KWAVE + ii;
    if (i >= NINSTR) i = 0;                    // dummy (never issued)
    const float* p;
    int lo;
    if (i < NXI) {                             // X slot
      const int s = i * 64 + l;                // LDS 16B-slot index
      const int c = s / 20, u = s - c * 20;
      const int qc = (c >> 3) & 3;
      int w4 = u - 5 * qc; if (w4 < 0) w4 += 20;
      p = xrow + (size_t)c * HW + (XW0 + w4 * 4);
      lo = i * 256;
    } else {                                   // Y slot
      const int s = (i - NXI) * 64 + l;
      int c, u, w4;
      if (YN4 == 32) { c = s >> 5; u = s & 31; w4 = u ^ (((c >> 3) & 3) << 1); }
      else { c = s / 20; u = s - c * 20; const int qc = (c >> 3) & 3;
             w4 = u - 5 * qc; if (w4 < 0) w4 += 20; }
      p = yrow + (size_t)c * HW + (YW0 + w4 * 4);
      lo = XWORDS + (i - NXI) * 256;
    }
    pv[ii] = (const char*)p;
    loff[ii] = lo;
  }
  int kc = NINSTR - wave * KWAVE;              // live instrs this wave (uniform)
  if (kc > KWAVE) kc = KWAVE;
  if (kc < 0) kc = 0;

  auto issue = [&](int buf) {                  // ~5-7 instrs, zero VGPR staging
#pragma unroll
    for (int ii = 0; ii < KWAVE; ++ii) {
      if (ii < kc) {
        gload_lds16(pv[ii], lds + buf * BUFWORDS + loff[ii]);
        pv[ii] += CBYTES;
      }
    }
  };

  // Per-wave single-chunk DMA count, for the counted wait.
  auto wait_chunk = [&]() {
    if (SEG == 0) waitcnt_vm<5>();             // all waves kc=5
    else if (wave < 3) waitcnt_vm<7>();        // waves 0-2: kc=7
    else waitcnt_vm<5>();                      // wave 3: kc=5
  };

  f32x4 acc[2][4] = {};

  auto compute = [&](int buf) {
    const float* BX = lds + buf * BUFWORDS;
    const float* BY = BX + XWORDS;
#pragma unroll
    for (int i = 0; i < 2; ++i) {
      const int wtl = wave + i * 4;            // local tile 0..4
      if (wtl > 4) continue;                   // only wave0 runs i=1
      float fa[8];
      {
        const int w4a = wtl * 4 + (m >> 2);
        int ua = w4a + 5 * q; if (ua >= 20) ua -= 20;
        const int base = q * 640 + ua * 4 + (m & 3);
#pragma unroll
        for (int j = 0; j < 8; ++j) fa[j] = BX[base + j * 80];
      }
      const s16x8 a = pack8(fa);
#pragma unroll
      for (int ss = 0; ss < 4; ++ss) {
        const int st = WT0 + wtl - 3 + ss;
        if (SEG > 0 || st >= 0) {              // SEG>0: st always >= 2
          float fb[8];
          const int w4b = ((st * 16 - YW0) >> 2) + (m >> 2);
          if (YN4 == 32) {
            const int ub = w4b ^ (q << 1);
            const int base = q * 1024 + ub * 4 + (m & 3);
#pragma unroll
            for (int j = 0; j < 8; ++j) fb[j] = BY[base + j * 128];
          } else {
            int ub = w4b + 5 * q; if (ub >= 20) ub -= 20;
            const int base = q * 640 + ub * 4 + (m & 3);
#pragma unroll
            for (int j = 0; j < 8; ++j) fb[j] = BY[base + j * 80];
          }
          const s16x8 b = pack8(fb);
          acc[i][ss] = __builtin_amdgcn_mfma_f32_16x16x32_bf16(a, b, acc[i][ss], 0, 0, 0);
        }
      }
    }
  };

  // Pipelined loop (T3 minimum + T4 counted vmcnt): chunk k+1's DMAs stay in
  // flight across compute(k); each chunk gets a full chunk-period to land.
  issue(0);                                    // c0 -> b0
  for (int k = 0; k < NCHUNK; ++k) {
    __builtin_amdgcn_s_barrier();              // all compute(k-1) reads done
    if (k + 1 < NCHUNK) {
      issue((k + 1) & 1);                      // c_{k+1} -> other buffer
      wait_chunk();                            // oldest (c_k) complete; c_{k+1} flying
    } else {
      waitcnt_vm<0>();                         // last chunk: drain
    }
    __builtin_amdgcn_s_barrier();              // c_k visible to all waves
    compute(k & 1);
  }

  // Epilogue: d = wi - wj; virtual tiles (st<0, SEG0) emit the w<d zeros.
#pragma unroll
  for (int i = 0; i < 2; ++i) {
    const int wtl = wave + i * 4;
    if (wtl > 4) continue;
    const int wt = WT0 + wtl;
#pragma unroll
    for (int ss = 0; ss < 4; ++ss) {
      const int st = wt - 3 + ss;
      const int wj = st * 16 + m;
#pragma unroll
      for (int r = 0; r < 4; ++r) {
        const int wi = wt * 16 + q * 4 + r;    // C/D: row=(lane>>4)*4+reg (m89)
        const int d = wi - wj;
        if (d >= 0 && d < ND) {
          const float v = (st >= 0) ? acc[i][ss][r] : 0.0f;
          orow[(size_t)d * (NB * HW) + wi] = v;
        }
      }
    }
  }
}

__global__ __launch_bounds__(256) void cv_kernel(const float* __restrict__ X,
                                                 const float* __restrict__ Y,
                                                 float* __restrict__ O) {
  __shared__ float lds[2 * BUFWORDS];  // 53248 B -> 3 blocks/CU
  const int tid = threadIdx.x;
  const int bid = blockIdx.x;
  // XCD-chunked bijective swizzle (1536 = 8*192): a row's 3 segments are
  // logical-consecutive -> same XCD L2 absorbs the Y band overlap.
  const int logical = (bid & 7) * 192 + (bid >> 3);
  const int row = logical / 3;    // 0..511 = b*128 + h
  const int seg = logical % 3;
  const int b = row >> 7, h = row & 127;
  const float* xrow = X + (size_t)b * NC * HW + (size_t)h * NW;
  const float* yrow = Y + (size_t)b * NC * HW + (size_t)h * NW;
  float* orow = O + ((size_t)b * NH + h) * NW;
  if (seg == 0)      cv_body<0>(xrow, yrow, orow, lds, tid);
  else if (seg == 1) cv_body<1>(xrow, yrow, orow, lds, tid);
  else               cv_body<2>(xrow, yrow, orow, lds, tid);
}

extern "C" void kernel_launch(void* const* d_in, const int* in_sizes, int n_in,
                              void* d_out, int out_size, void* d_ws, size_t ws_size,
                              hipStream_t stream) {
  const float* x = (const float*)d_in[0];
  const float* y = (const float*)d_in[1];
  float* out = (float*)d_out;
  cv_kernel<<<dim3(1536), dim3(256), 0, stream>>>(x, y, out);
}